// Round 2
// baseline (373.290 us; speedup 1.0000x reference)
//
#include <hip/hip_runtime.h>

#define HWD 256
#define HW2 (HWD * HWD)        // 65536 spatial positions per plane
#define NB 8                   // batch
#define NC 64                  // channels
#define PLANE4 (HW2 / 4)       // 16384 float4 per spatial plane

typedef float floatx4 __attribute__((ext_vector_type(4)));

// Partial-sum slices live in the `out` buffer (134 MB; blend overwrites it
// last, so it is free scratch until then).
// Layout (float4 units): P1[cg][b][p] then P2[cg][b][p], cg=0..3.
#define PSTRIDE ((size_t)NB * PLANE4)      // 131072 float4 per cg-slice

__device__ inline void acc_abs(float4& a, const float4 v) {
    a.x += fabsf(v.x); a.y += fabsf(v.y);
    a.z += fabsf(v.z); a.w += fabsf(v.w);
}

// ---------------------------------------------------------------------------
// Kernel 1: channel-group partial L1 norms.
// THEORY OF CHANGE: old version gave each block a 1KB spatial footprint x 64
// channels at 256KB stride -> ~16K concurrent 1KB-granule streams -> memory
// system at 2.7 TB/s effective with all pipes idle (VALUBusy 3.4%, VGPR 36).
// New geometry: grid 1024 = 8b x 4cg x 32tile. Each block sweeps an
// 8KB-CONTIGUOUS spatial stripe (512 float4) per channel visit, 16 channels.
// Channel visit order rotated per block to decorrelate the 256KB-stride
// phase across blocks (anti bank/channel aliasing).
// launch_bounds(256,4): allow up to 128 VGPRs so the scheduler can keep the
// 8-load cluster in flight (round-0 lesson: default occupancy targeting
// squeezed VGPRs to 36 and serialized the loads). sched_barrier(0) pins the
// cluster.
// ---------------------------------------------------------------------------
__global__ __launch_bounds__(256, 4)
void norms_partial_kernel(const float* __restrict__ x1,
                          const float* __restrict__ x2,
                          float* __restrict__ scratch) {
    const int tid  = threadIdx.x;
    const int blk  = blockIdx.x;          // [0, 1024)
    const int tile = blk & 31;
    const int cg   = (blk >> 5) & 3;
    const int b    = blk >> 7;
    const int rot  = blk & 7;             // channel-pair visit rotation

    const int p0 = tile * 512 + tid;      // float4 idx; 2nd position p0+256

    const size_t ibase = ((size_t)(b * NC + cg * 16)) * PLANE4 + p0;
    const float4* x1v = (const float4*)x1 + ibase;
    const float4* x2v = (const float4*)x2 + ibase;

    float4 a1a = make_float4(0.f, 0.f, 0.f, 0.f);
    float4 a1b = make_float4(0.f, 0.f, 0.f, 0.f);
    float4 a2a = make_float4(0.f, 0.f, 0.f, 0.f);
    float4 a2b = make_float4(0.f, 0.f, 0.f, 0.f);

#pragma unroll
    for (int pr = 0; pr < 8; ++pr) {
        const int c = ((pr + rot) & 7) * 2;          // channel pair (c, c+1)
        const size_t o0 = (size_t)c * PLANE4;
        const size_t o1 = o0 + PLANE4;
        float4 v0 = x1v[o0];
        float4 v1 = x1v[o0 + 256];
        float4 v2 = x2v[o0];
        float4 v3 = x2v[o0 + 256];
        float4 v4 = x1v[o1];
        float4 v5 = x1v[o1 + 256];
        float4 v6 = x2v[o1];
        float4 v7 = x2v[o1 + 256];
        __builtin_amdgcn_sched_barrier(0);           // keep 8 loads clustered
        acc_abs(a1a, v0); acc_abs(a1b, v1);
        acc_abs(a2a, v2); acc_abs(a2b, v3);
        acc_abs(a1a, v4); acc_abs(a1b, v5);
        acc_abs(a2a, v6); acc_abs(a2b, v7);
    }

    float4* P1 = (float4*)scratch + (size_t)cg * PSTRIDE + (size_t)b * PLANE4;
    float4* P2 = P1 + 4 * PSTRIDE;
    P1[p0]       = a1a;
    P1[p0 + 256] = a1b;
    P2[p0]       = a2a;
    P2[p0 + 256] = a2b;
}

// ---------------------------------------------------------------------------
// Kernel 1b: sum the 4 channel-group partials -> n1, n2 (L2-resident, 16 MB
// read + 4 MB write, ~10 us).
// grid: NB*PLANE4 / 256 = 512 blocks
// ---------------------------------------------------------------------------
__global__ void sum_partials_kernel(const float* __restrict__ scratch,
                                    float* __restrict__ n1,
                                    float* __restrict__ n2) {
    const size_t t = (size_t)blockIdx.x * 256 + threadIdx.x;  // [0, 131072)
    const float4* P = (const float4*)scratch;

    float4 u0 = P[0 * PSTRIDE + t];
    float4 u1 = P[1 * PSTRIDE + t];
    float4 u2 = P[2 * PSTRIDE + t];
    float4 u3 = P[3 * PSTRIDE + t];
    float4 s1;
    s1.x = (u0.x + u1.x) + (u2.x + u3.x);
    s1.y = (u0.y + u1.y) + (u2.y + u3.y);
    s1.z = (u0.z + u1.z) + (u2.z + u3.z);
    s1.w = (u0.w + u1.w) + (u2.w + u3.w);

    float4 w0 = P[4 * PSTRIDE + t];
    float4 w1 = P[5 * PSTRIDE + t];
    float4 w2 = P[6 * PSTRIDE + t];
    float4 w3 = P[7 * PSTRIDE + t];
    float4 s2;
    s2.x = (w0.x + w1.x) + (w2.x + w3.x);
    s2.y = (w0.y + w1.y) + (w2.y + w3.y);
    s2.z = (w0.z + w1.z) + (w2.z + w3.z);
    s2.w = (w0.w + w1.w) + (w2.w + w3.w);

    ((float4*)n1)[t] = s1;
    ((float4*)n2)[t] = s2;
}

// ---------------------------------------------------------------------------
// Kernel 2: 3x3 conv (zero pad, taps from w) + bias on n1,n2; emit
// r = c1 / (c1 + c2). float4-ized: each thread produces 4 consecutive
// outputs; per row it loads 1 aligned float4 + 2 boundary scalars per array.
// Working set (4 MiB in, 2 MiB out) is L2/L3-resident. (unchanged)
// grid: NB * HW2 / 4 / 256 = 512 blocks
// ---------------------------------------------------------------------------
__global__ void conv_ratio_kernel(const float* __restrict__ n1,
                                  const float* __restrict__ n2,
                                  const float* __restrict__ w,
                                  const float* __restrict__ bias,
                                  float* __restrict__ r) {
    int t = blockIdx.x * blockDim.x + threadIdx.x;   // [0, NB*HW2/4)
    int b = t >> 14;                                  // HW2/4 = 16384 per batch
    int sp = t & ((HW2 / 4) - 1);
    int y = sp >> 6;                                  // 64 float4 per row
    int x0 = (sp & 63) << 2;                          // leftmost pixel of the 4

    const float* p1 = n1 + (size_t)b * HW2;
    const float* p2 = n2 + (size_t)b * HW2;

    float o1[4] = {0.f, 0.f, 0.f, 0.f};
    float o2[4] = {0.f, 0.f, 0.f, 0.f};

#pragma unroll
    for (int dy = -1; dy <= 1; ++dy) {
        int yy = y + dy;
        if (yy < 0 || yy >= HWD) continue;   // zero pad
        const float* r1 = p1 + yy * HWD;
        const float* r2 = p2 + yy * HWD;
        float4 m1 = *(const float4*)(r1 + x0);
        float4 m2 = *(const float4*)(r2 + x0);
        float e1[6], e2[6];
        e1[0] = (x0 > 0) ? r1[x0 - 1] : 0.f;
        e2[0] = (x0 > 0) ? r2[x0 - 1] : 0.f;
        e1[1] = m1.x; e1[2] = m1.y; e1[3] = m1.z; e1[4] = m1.w;
        e2[1] = m2.x; e2[2] = m2.y; e2[3] = m2.z; e2[4] = m2.w;
        e1[5] = (x0 + 4 < HWD) ? r1[x0 + 4] : 0.f;
        e2[5] = (x0 + 4 < HWD) ? r2[x0 + 4] : 0.f;
        const float* wr = w + (dy + 1) * 3;
#pragma unroll
        for (int j = 0; j < 4; ++j) {
#pragma unroll
            for (int k = 0; k < 3; ++k) {
                o1[j] += wr[k] * e1[j + k];
                o2[j] += wr[k] * e2[j + k];
            }
        }
    }

    float bv = bias[0];
    float4 out;
    { float c1 = o1[0] + bv, c2 = o2[0] + bv; out.x = c1 / (c1 + c2); }
    { float c1 = o1[1] + bv, c2 = o2[1] + bv; out.y = c1 / (c1 + c2); }
    { float c1 = o1[2] + bv, c2 = o2[2] + bv; out.z = c1 / (c1 + c2); }
    { float c1 = o1[3] + bv, c2 = o2[3] + bv; out.w = c1 / (c1 + c2); }
    ((float4*)r)[t] = out;
}

// ---------------------------------------------------------------------------
// Kernel 3: out = x1 * r + x2 * (1 - r), linear float4 streaming sweep.
// (unchanged) grid: 8192 blocks x 256 threads x 4 iters.
// ---------------------------------------------------------------------------
#define BLEND_BLOCKS 8192
#define BLEND_STRIDE ((size_t)BLEND_BLOCKS * 256)

__global__ void blend_kernel(const float* __restrict__ x1,
                             const float* __restrict__ x2,
                             const float* __restrict__ r,
                             float* __restrict__ out) {
    size_t idx = (size_t)blockIdx.x * 256 + threadIdx.x;
    const float4* x1v = (const float4*)x1;
    const float4* x2v = (const float4*)x2;
    const float4* rv4 = (const float4*)r;
    floatx4* ov = (floatx4*)out;

#pragma unroll
    for (int k = 0; k < 4; ++k) {
        size_t i = idx + (size_t)k * BLEND_STRIDE;
        int b = (int)(i >> 20);              // NC*PLANE4 = 2^20 float4/batch
        int p = (int)(i & (PLANE4 - 1));
        float4 rv = rv4[((size_t)b << 14) + p];
        float4 v1 = x1v[i];
        float4 v2 = x2v[i];
        floatx4 o;
        o.x = v1.x * rv.x + v2.x * (1.f - rv.x);
        o.y = v1.y * rv.y + v2.y * (1.f - rv.y);
        o.z = v1.z * rv.z + v2.z * (1.f - rv.z);
        o.w = v1.w * rv.w + v2.w * (1.f - rv.w);
        __builtin_nontemporal_store(o, ov + i);
    }
}

extern "C" void kernel_launch(void* const* d_in, const int* in_sizes, int n_in,
                              void* d_out, int out_size, void* d_ws, size_t ws_size,
                              hipStream_t stream) {
    const float* x1 = (const float*)d_in[0];
    const float* x2 = (const float*)d_in[1];
    const float* w  = (const float*)d_in[2];
    const float* bv = (const float*)d_in[3];
    float* out = (float*)d_out;

    // workspace layout: n1 | n2 | r, each NB*HW2 floats (2 MiB)
    float* n1 = (float*)d_ws;
    float* n2 = n1 + (size_t)NB * HW2;
    float* r  = n2 + (size_t)NB * HW2;

    const int block = 256;

    // partials staged in `out` (fully overwritten by blend afterwards)
    norms_partial_kernel<<<1024, block, 0, stream>>>(x1, x2, out);
    sum_partials_kernel<<<512, block, 0, stream>>>(out, n1, n2);
    conv_ratio_kernel<<<NB * HW2 / 4 / block, block, 0, stream>>>(n1, n2, w, bv, r);
    blend_kernel<<<BLEND_BLOCKS, block, 0, stream>>>(x1, x2, r, out);
}

// Round 3
// 360.214 us; speedup vs baseline: 1.0363x; 1.0363x over previous
//
#include <hip/hip_runtime.h>

#define HWD 256
#define HW2 (HWD * HWD)        // 65536 spatial positions per plane
#define NB 8                   // batch
#define NC 64                  // channels
#define PLANE4 (HW2 / 4)       // 16384 float4 per spatial plane

typedef float floatx4 __attribute__((ext_vector_type(4)));

// ---------------------------------------------------------------------------
// Kernel 1: channel-wise L1 norms, input-split, max-occupancy thin waves.
// THEORY: R0 (1KB granules, 36 VGPR, ~17 waves/CU) and R2 (8KB granules,
// 64 VGPR, 8-deep clusters, ~12-16 waves/CU) both delivered ~2.5 TB/s ->
// neither granule size nor per-wave MLP is the knob. Delivered BW appears to
// scale with RESIDENT WAVES (m13's 6.3 TB/s = thin waves at 32/CU). So:
// minimal per-thread state (one accumulator, 16 loads, VGPR ~24),
// launch_bounds(256,8) to request 8 waves/SIMD, 4096 blocks (16/CU queued),
// and each block reads only ONE input (halves stream interleaving per CU).
// grid = 2 inputs x 8 batch x 256 tiles = 4096 blocks.
// ---------------------------------------------------------------------------
__global__ __launch_bounds__(256, 8)
void norms_kernel(const float* __restrict__ x1,
                  const float* __restrict__ x2,
                  float* __restrict__ n1,
                  float* __restrict__ n2) {
    const int t = threadIdx.x;
    const int s = t & 63;            // spatial float4 within tile
    const int g = t >> 6;            // wave id = channel group (0..3)
    const int blk = blockIdx.x;
    const int tile = blk & 255;      // 256 tiles of 64 float4 per plane
    const int b = (blk >> 8) & 7;
    const int inp = blk >> 11;       // 0 -> x1, 1 -> x2

    const int p = tile * 64 + s;     // float4 index within plane
    const float* x = inp ? x2 : x1;
    const float4* xv = (const float4*)x +
                       ((size_t)(b * NC + g * 16)) * PLANE4 + p;

    float4 a = make_float4(0.f, 0.f, 0.f, 0.f);
#pragma unroll
    for (int c = 0; c < 16; ++c) {
        float4 v = xv[(size_t)c * PLANE4];
        a.x += fabsf(v.x); a.y += fabsf(v.y);
        a.z += fabsf(v.z); a.w += fabsf(v.w);
    }

    __shared__ float4 red[4][64];
    red[g][s] = a;
    __syncthreads();

    if (g == 0) {
        float4 r0 = red[0][s], r1 = red[1][s], r2 = red[2][s], r3 = red[3][s];
        float4 o;
        o.x = (r0.x + r1.x) + (r2.x + r3.x);
        o.y = (r0.y + r1.y) + (r2.y + r3.y);
        o.z = (r0.z + r1.z) + (r2.z + r3.z);
        o.w = (r0.w + r1.w) + (r2.w + r3.w);
        float* n = inp ? n2 : n1;
        ((float4*)n)[(size_t)b * PLANE4 + p] = o;
    }
}

// ---------------------------------------------------------------------------
// Kernel 2: 3x3 conv (zero pad) + bias on n1,n2; emit r = c1/(c1+c2).
// float4-ized, L2/L3-resident working set. (unchanged from round 1)
// grid: NB * HW2 / 4 / 256 = 512 blocks
// ---------------------------------------------------------------------------
__global__ void conv_ratio_kernel(const float* __restrict__ n1,
                                  const float* __restrict__ n2,
                                  const float* __restrict__ w,
                                  const float* __restrict__ bias,
                                  float* __restrict__ r) {
    int t = blockIdx.x * blockDim.x + threadIdx.x;   // [0, NB*HW2/4)
    int b = t >> 14;                                  // HW2/4 = 16384 per batch
    int sp = t & ((HW2 / 4) - 1);
    int y = sp >> 6;                                  // 64 float4 per row
    int x0 = (sp & 63) << 2;                          // leftmost pixel of the 4

    const float* p1 = n1 + (size_t)b * HW2;
    const float* p2 = n2 + (size_t)b * HW2;

    float o1[4] = {0.f, 0.f, 0.f, 0.f};
    float o2[4] = {0.f, 0.f, 0.f, 0.f};

#pragma unroll
    for (int dy = -1; dy <= 1; ++dy) {
        int yy = y + dy;
        if (yy < 0 || yy >= HWD) continue;   // zero pad
        const float* r1 = p1 + yy * HWD;
        const float* r2 = p2 + yy * HWD;
        float4 m1 = *(const float4*)(r1 + x0);
        float4 m2 = *(const float4*)(r2 + x0);
        float e1[6], e2[6];
        e1[0] = (x0 > 0) ? r1[x0 - 1] : 0.f;
        e2[0] = (x0 > 0) ? r2[x0 - 1] : 0.f;
        e1[1] = m1.x; e1[2] = m1.y; e1[3] = m1.z; e1[4] = m1.w;
        e2[1] = m2.x; e2[2] = m2.y; e2[3] = m2.z; e2[4] = m2.w;
        e1[5] = (x0 + 4 < HWD) ? r1[x0 + 4] : 0.f;
        e2[5] = (x0 + 4 < HWD) ? r2[x0 + 4] : 0.f;
        const float* wr = w + (dy + 1) * 3;
#pragma unroll
        for (int j = 0; j < 4; ++j) {
#pragma unroll
            for (int k = 0; k < 3; ++k) {
                o1[j] += wr[k] * e1[j + k];
                o2[j] += wr[k] * e2[j + k];
            }
        }
    }

    float bv = bias[0];
    float4 out;
    { float c1 = o1[0] + bv, c2 = o2[0] + bv; out.x = c1 / (c1 + c2); }
    { float c1 = o1[1] + bv, c2 = o2[1] + bv; out.y = c1 / (c1 + c2); }
    { float c1 = o1[2] + bv, c2 = o2[2] + bv; out.z = c1 / (c1 + c2); }
    { float c1 = o1[3] + bv, c2 = o2[3] + bv; out.w = c1 / (c1 + c2); }
    ((float4*)r)[t] = out;
}

// ---------------------------------------------------------------------------
// Kernel 3: out = x1 * r + x2 * (1 - r), linear float4 streaming sweep.
// m13 recipe: thin waves (no unroll -> ~20 VGPR; the 3 loads inside one
// iteration already overlap), launch_bounds(256,8), exactly 2048 blocks =
// 32 waves/CU chip fill, grid-stride x16, NT stores.
// ---------------------------------------------------------------------------
#define BLEND_BLOCKS 2048
#define BLEND_STRIDE ((size_t)BLEND_BLOCKS * 256)   // 524288 threads

__global__ __launch_bounds__(256, 8)
void blend_kernel(const float* __restrict__ x1,
                  const float* __restrict__ x2,
                  const float* __restrict__ r,
                  float* __restrict__ out) {
    size_t idx = (size_t)blockIdx.x * 256 + threadIdx.x;
    const float4* x1v = (const float4*)x1;
    const float4* x2v = (const float4*)x2;
    const float4* rv4 = (const float4*)r;
    floatx4* ov = (floatx4*)out;

#pragma unroll 1
    for (int k = 0; k < 16; ++k) {
        size_t i = idx + (size_t)k * BLEND_STRIDE;
        int b = (int)(i >> 20);              // NC*PLANE4 = 2^20 float4/batch
        int p = (int)(i & (PLANE4 - 1));
        float4 v1 = x1v[i];
        float4 v2 = x2v[i];
        float4 rv = rv4[((size_t)b << 14) + p];
        floatx4 o;
        o.x = v1.x * rv.x + v2.x * (1.f - rv.x);
        o.y = v1.y * rv.y + v2.y * (1.f - rv.y);
        o.z = v1.z * rv.z + v2.z * (1.f - rv.z);
        o.w = v1.w * rv.w + v2.w * (1.f - rv.w);
        __builtin_nontemporal_store(o, ov + i);
    }
}

extern "C" void kernel_launch(void* const* d_in, const int* in_sizes, int n_in,
                              void* d_out, int out_size, void* d_ws, size_t ws_size,
                              hipStream_t stream) {
    const float* x1 = (const float*)d_in[0];
    const float* x2 = (const float*)d_in[1];
    const float* w  = (const float*)d_in[2];
    const float* bv = (const float*)d_in[3];
    float* out = (float*)d_out;

    // workspace layout: n1 | n2 | r, each NB*HW2 floats (2 MiB)
    float* n1 = (float*)d_ws;
    float* n2 = n1 + (size_t)NB * HW2;
    float* r  = n2 + (size_t)NB * HW2;

    const int block = 256;

    norms_kernel<<<2 * NB * 256, block, 0, stream>>>(x1, x2, n1, n2);
    conv_ratio_kernel<<<NB * HW2 / 4 / block, block, 0, stream>>>(n1, n2, w, bv, r);
    blend_kernel<<<BLEND_BLOCKS, block, 0, stream>>>(x1, x2, r, out);
}

// Round 5
// 346.493 us; speedup vs baseline: 1.0773x; 1.0396x over previous
//
#include <hip/hip_runtime.h>

#define HWD 256
#define HW2 (HWD * HWD)        // 65536 spatial positions per plane
#define NB 8                   // batch
#define NC 64                  // channels
#define PLANE4 (HW2 / 4)       // 16384 float4 per spatial plane

typedef float floatx4 __attribute__((ext_vector_type(4)));

// ---------------------------------------------------------------------------
// Kernel 1: channel-wise L1 norms — R3 body exactly, plus NON-TEMPORAL loads.
// THEORY (round 4): granule size, per-wave MLP, and occupancy are all proven
// non-knobs (R0/R1/R2 all ~2.75 TB/s effective). Blend sweeps the same bytes
// linearly at >4.3 TB/s, so the wall is specific to this scattered-granule,
// 50%-L3-hit pattern. Hypothesis: normal-allocation misses churn the
// slightly-over-capacity MALL (268MB data vs 256MB L3) and hit/miss
// interleave serializes slice queues. nt loads -> streaming/evict-first
// policy, decoupling the miss stream from the L3 state.
// Single-variable A/B vs R3: only the load policy changed.
// grid = 2 inputs x 8 batch x 256 tiles = 4096 blocks.
// ---------------------------------------------------------------------------
__global__ __launch_bounds__(256, 8)
void norms_kernel(const float* __restrict__ x1,
                  const float* __restrict__ x2,
                  float* __restrict__ n1,
                  float* __restrict__ n2) {
    const int t = threadIdx.x;
    const int s = t & 63;            // spatial float4 within tile
    const int g = t >> 6;            // wave id = channel group (0..3)
    const int blk = blockIdx.x;
    const int tile = blk & 255;      // 256 tiles of 64 float4 per plane
    const int b = (blk >> 8) & 7;
    const int inp = blk >> 11;       // 0 -> x1, 1 -> x2

    const int p = tile * 64 + s;     // float4 index within plane
    const float* x = inp ? x2 : x1;
    const floatx4* xv = (const floatx4*)x +
                        ((size_t)(b * NC + g * 16)) * PLANE4 + p;

    float4 a = make_float4(0.f, 0.f, 0.f, 0.f);
#pragma unroll
    for (int c = 0; c < 16; ++c) {
        floatx4 v = __builtin_nontemporal_load(xv + (size_t)c * PLANE4);
        a.x += fabsf(v.x); a.y += fabsf(v.y);
        a.z += fabsf(v.z); a.w += fabsf(v.w);
    }

    __shared__ float4 red[4][64];
    red[g][s] = a;
    __syncthreads();

    if (g == 0) {
        float4 r0 = red[0][s], r1 = red[1][s], r2 = red[2][s], r3 = red[3][s];
        float4 o;
        o.x = (r0.x + r1.x) + (r2.x + r3.x);
        o.y = (r0.y + r1.y) + (r2.y + r3.y);
        o.z = (r0.z + r1.z) + (r2.z + r3.z);
        o.w = (r0.w + r1.w) + (r2.w + r3.w);
        float* n = inp ? n2 : n1;
        ((float4*)n)[(size_t)b * PLANE4 + p] = o;
    }
}

// ---------------------------------------------------------------------------
// Kernel 2: 3x3 conv (zero pad) + bias on n1,n2; emit r = c1/(c1+c2).
// float4-ized, L2/L3-resident working set. (unchanged)
// grid: NB * HW2 / 4 / 256 = 512 blocks
// ---------------------------------------------------------------------------
__global__ void conv_ratio_kernel(const float* __restrict__ n1,
                                  const float* __restrict__ n2,
                                  const float* __restrict__ w,
                                  const float* __restrict__ bias,
                                  float* __restrict__ r) {
    int t = blockIdx.x * blockDim.x + threadIdx.x;   // [0, NB*HW2/4)
    int b = t >> 14;                                  // HW2/4 = 16384 per batch
    int sp = t & ((HW2 / 4) - 1);
    int y = sp >> 6;                                  // 64 float4 per row
    int x0 = (sp & 63) << 2;                          // leftmost pixel of the 4

    const float* p1 = n1 + (size_t)b * HW2;
    const float* p2 = n2 + (size_t)b * HW2;

    float o1[4] = {0.f, 0.f, 0.f, 0.f};
    float o2[4] = {0.f, 0.f, 0.f, 0.f};

#pragma unroll
    for (int dy = -1; dy <= 1; ++dy) {
        int yy = y + dy;
        if (yy < 0 || yy >= HWD) continue;   // zero pad
        const float* r1 = p1 + yy * HWD;
        const float* r2 = p2 + yy * HWD;
        float4 m1 = *(const float4*)(r1 + x0);
        float4 m2 = *(const float4*)(r2 + x0);
        float e1[6], e2[6];
        e1[0] = (x0 > 0) ? r1[x0 - 1] : 0.f;
        e2[0] = (x0 > 0) ? r2[x0 - 1] : 0.f;
        e1[1] = m1.x; e1[2] = m1.y; e1[3] = m1.z; e1[4] = m1.w;
        e2[1] = m2.x; e2[2] = m2.y; e2[3] = m2.z; e2[4] = m2.w;
        e1[5] = (x0 + 4 < HWD) ? r1[x0 + 4] : 0.f;
        e2[5] = (x0 + 4 < HWD) ? r2[x0 + 4] : 0.f;
        const float* wr = w + (dy + 1) * 3;
#pragma unroll
        for (int j = 0; j < 4; ++j) {
#pragma unroll
            for (int k = 0; k < 3; ++k) {
                o1[j] += wr[k] * e1[j + k];
                o2[j] += wr[k] * e2[j + k];
            }
        }
    }

    float bv = bias[0];
    float4 out;
    { float c1 = o1[0] + bv, c2 = o2[0] + bv; out.x = c1 / (c1 + c2); }
    { float c1 = o1[1] + bv, c2 = o2[1] + bv; out.y = c1 / (c1 + c2); }
    { float c1 = o1[2] + bv, c2 = o2[2] + bv; out.z = c1 / (c1 + c2); }
    { float c1 = o1[3] + bv, c2 = o2[3] + bv; out.w = c1 / (c1 + c2); }
    ((float4*)r)[t] = out;
}

// ---------------------------------------------------------------------------
// Kernel 3: out = x1 * r + x2 * (1 - r), linear float4 streaming sweep.
// R3 body + nt loads on the x1/x2 streams (read-once data; keep them out of
// the caches). r load stays cached (8MB, re-read nothing but L2-hot).
// grid: 2048 blocks x 256 threads x 16 iters, NT stores.
// ---------------------------------------------------------------------------
#define BLEND_BLOCKS 2048
#define BLEND_STRIDE ((size_t)BLEND_BLOCKS * 256)   // 524288 threads

__global__ __launch_bounds__(256, 8)
void blend_kernel(const float* __restrict__ x1,
                  const float* __restrict__ x2,
                  const float* __restrict__ r,
                  float* __restrict__ out) {
    size_t idx = (size_t)blockIdx.x * 256 + threadIdx.x;
    const floatx4* x1v = (const floatx4*)x1;
    const floatx4* x2v = (const floatx4*)x2;
    const float4* rv4 = (const float4*)r;
    floatx4* ov = (floatx4*)out;

#pragma unroll 1
    for (int k = 0; k < 16; ++k) {
        size_t i = idx + (size_t)k * BLEND_STRIDE;
        int b = (int)(i >> 20);              // NC*PLANE4 = 2^20 float4/batch
        int p = (int)(i & (PLANE4 - 1));
        floatx4 v1 = __builtin_nontemporal_load(x1v + i);
        floatx4 v2 = __builtin_nontemporal_load(x2v + i);
        float4 rv = rv4[((size_t)b << 14) + p];
        floatx4 o;
        o.x = v1.x * rv.x + v2.x * (1.f - rv.x);
        o.y = v1.y * rv.y + v2.y * (1.f - rv.y);
        o.z = v1.z * rv.z + v2.z * (1.f - rv.z);
        o.w = v1.w * rv.w + v2.w * (1.f - rv.w);
        __builtin_nontemporal_store(o, ov + i);
    }
}

extern "C" void kernel_launch(void* const* d_in, const int* in_sizes, int n_in,
                              void* d_out, int out_size, void* d_ws, size_t ws_size,
                              hipStream_t stream) {
    const float* x1 = (const float*)d_in[0];
    const float* x2 = (const float*)d_in[1];
    const float* w  = (const float*)d_in[2];
    const float* bv = (const float*)d_in[3];
    float* out = (float*)d_out;

    // workspace layout: n1 | n2 | r, each NB*HW2 floats (2 MiB)
    float* n1 = (float*)d_ws;
    float* n2 = n1 + (size_t)NB * HW2;
    float* r  = n2 + (size_t)NB * HW2;

    const int block = 256;

    norms_kernel<<<2 * NB * 256, block, 0, stream>>>(x1, x2, n1, n2);
    conv_ratio_kernel<<<NB * HW2 / 4 / block, block, 0, stream>>>(n1, n2, w, bv, r);
    blend_kernel<<<BLEND_BLOCKS, block, 0, stream>>>(x1, x2, r, out);
}